// Round 8
// baseline (478.775 us; speedup 1.0000x reference)
//
#include <hip/hip_runtime.h>
#include <hip/hip_fp16.h>

// MultiScaleDeformableAttention forward (Deformable-DETR), fp32 in/out.
// B=4, S=21760, H=8, D=32, Q=10000, L=4, P=4.
// Levels (static): (128,128),(64,64),(32,32),(16,16); starts 0,16384,20480,21504.
//
// Round 13 == round 12 resubmitted verbatim (broker timeout, never measured).
// Evidence so far: LDS offload of lv2+3 works (112us best vs 206 baseline);
// big-dynamic-LDS kernels pinned at 1 WG/CU (2x80KB and 2x64KB both fail to
// co-schedule); lv3 via global cost +21us despite L1 residency (L1 hits eat
// VMEM slots -> LDS pipe cheaper); at 112us nothing saturated (VALU 46%,
// HBM 15%) -> latency-bound at 2 waves/SIMD.
// This round: ILP attack at fixed occupancy.
//   - __launch_bounds__(512,1): VGPR cap 128->~256 (120/128 was starved).
//   - dual-query per thread: 2 accumulators, interleaved corner loads ->
//     2x outstanding requests per wave.
//   - grid 256 = exactly 1 block/CU, single round (no 2-round tail).
// Measured launch_bounds map: (512,2)->120 ok, (512,4)->64 spill,
// (1024,1)->64 spill. 512 threads is the only no-spill shape.
// Fallbacks: no big-LDS attr -> round-5 fp16 kernel; small ws -> fp32 kernel.

#define MSDA_B 4
#define MSDA_Q 10000
#define MSDA_H 8
#define MSDA_D 32
#define MSDA_L 4
#define MSDA_P 4
#define MSDA_S 21760

#define MSDA_QBLK16 157   // ceil(10000/64) q-blocks per (b,h) (round-5 fp16 path)
#define MSDA_QBLK32 313   // ceil(10000/32) (fp32 fallback path)

#define MSDA_NB 8         // q-chunks per (b,h) slice (LDS path)
#define MSDA_QPC 1250     // queries per chunk; 8*1250 = 10000 exactly
#define MSDA_LDS_BYTES 81920  // levels 2+3: 1280 pixels * 64 B

// ---------------- pre-pass: fp32 [B,S,H,D] -> fp16 [B,H,S,D] ----------------
__global__ __launch_bounds__(256) void msda_convert_kernel(
    const float* __restrict__ value, __half* __restrict__ vw)
{
    int o4 = blockIdx.x * 256 + threadIdx.x;      // index of 4 halves in output
    int d4 = o4 & 7;                               // D/4 = 8
    int rest = o4 >> 3;                            // (b*H + h)*S + s
    int s = rest % MSDA_S;
    int bh = rest / MSDA_S;
    int b = bh >> 3, h = bh & 7;
    float4 v = *(const float4*)(value +
        (((size_t)b * MSDA_S + s) * MSDA_H + h) * MSDA_D + 4 * d4);
    union { __half2 h2[2]; uint2 u; } pk;
    pk.h2[0] = __floats2half2_rn(v.x, v.y);
    pk.h2[1] = __floats2half2_rn(v.z, v.w);
    ((uint2*)vw)[o4] = pk.u;
}

// ---------------- main kernel (fp16 gather + LDS levels 2,3; dual-query) ----
__global__ __launch_bounds__(512, 1) void msda_fwd_lds_kernel(
    const __half* __restrict__ vw,     // [B,H,S,D] fp16
    const float* __restrict__ loc,     // [B,Q,H,L,P,2]
    const float* __restrict__ aw,      // [B,Q,H,L,P]
    float* __restrict__ out)           // [B,Q,H,D]
{
    constexpr int H = MSDA_H, D = MSDA_D, L = MSDA_L, P = MSDA_P;
    constexpr int Q = MSDA_Q, S = MSDA_S;
    const int lvl_sh[4]     = {7, 6, 5, 4};
    const int lvl_start[4]  = {0, 16384, 20480, 21504};
    const int lvl_lstart[4] = {0, 0, 0, 1024};   // local pixel base in LDS (l>=2)

    extern __shared__ char smem[];

    // XCD-affine: blockIdx%8 = XCD = head. 256 blocks = 1 per CU.
    int i = blockIdx.x;
    int h = i & 7;
    int r = i >> 3;                     // [0,32)
    int qc = r & (MSDA_NB - 1);         // [0,8)
    int b = r >> 3;                     // [0,4)

    const size_t slice = (size_t)(b * H + h) * S * D;   // in halves

    // ---- stage levels 2+3 (pixels 20480..21759, 80KB contiguous) ----
    {
        const uint4* src = (const uint4*)(vw + slice + (size_t)20480 * D);
        uint4* dst = (uint4*)smem;
#pragma unroll
        for (int k = 0; k < 10; ++k)                     // 10*512 = 5120 uint4
            dst[threadIdx.x + 512 * k] = src[threadIdx.x + 512 * k];
    }
    __syncthreads();

    const int lane = threadIdx.x & 3;
    const unsigned coff = (unsigned)lane * 16;    // 16B = 8 halves = d[8k..8k+7]
    const int qsub = threadIdx.x >> 2;            // quad id [0,128)
    const char* vb = (const char*)(vw + slice);

    const int qcbase = qc * MSDA_QPC;

    for (int it = 0; it < 5; ++it) {
        // two consecutive queries per quad; 256 queries per iteration
        int off = it * 256 + 2 * qsub;            // even, [0,1280)
        bool valid = off < MSDA_QPC;              // 1250 limit (both q's, off even)
        int offc = valid ? off : (MSDA_QPC - 2);  // clamp to 1248 (harmless dup)
        int qA = qcbase + offc;
        int qB = qA + 1;

        const size_t bqhA = ((size_t)b * Q + qA) * H + h;
        const size_t bqhB = ((size_t)b * Q + qB) * H + h;
        const float4* lpA = (const float4*)(loc + bqhA * (L * P * 2));
        const float4* wpA = (const float4*)(aw  + bqhA * (L * P));
        const float4* lpB = (const float4*)(loc + bqhB * (L * P * 2));
        const float4* wpB = (const float4*)(aw  + bqhB * (L * P));

        float2 accA[4] = {{0.f,0.f},{0.f,0.f},{0.f,0.f},{0.f,0.f}};
        float2 accB[4] = {{0.f,0.f},{0.f,0.f},{0.f,0.f},{0.f,0.f}};

#pragma unroll
        for (int l = 0; l < L; ++l) {
            const int sh = lvl_sh[l];
            const int hw = 1 << sh;
            const float fhw = (float)hw;

            float4 laA = lpA[2 * l + 0], lbA = lpA[2 * l + 1], wvA = wpA[l];
            float4 laB = lpB[2 * l + 0], lbB = lpB[2 * l + 1], wvB = wpB[l];
            float lxA[4] = {laA.x, laA.z, lbA.x, lbA.z};
            float lyA[4] = {laA.y, laA.w, lbA.y, lbA.w};
            float wlA[4] = {wvA.x, wvA.y, wvA.z, wvA.w};
            float lxB[4] = {laB.x, laB.z, lbB.x, lbB.z};
            float lyB[4] = {laB.y, laB.w, lbB.y, lbB.w};
            float wlB[4] = {wvB.x, wvB.y, wvB.z, wvB.w};

#pragma unroll
            for (int p = 0; p < P; ++p) {
                // ---- coords A ----
                float xA = lxA[p] * fhw - 0.5f, yA = lyA[p] * fhw - 0.5f;
                float xfA = floorf(xA), yfA = floorf(yA);
                float fxA = xA - xfA, fyA = yA - yfA;
                int x0A = (int)xfA, y0A = (int)yfA;
                int x1A = x0A + 1, y1A = y0A + 1;
                float vx0A = ((unsigned)x0A < (unsigned)hw) ? 1.f : 0.f;
                float vx1A = ((unsigned)x1A < (unsigned)hw) ? 1.f : 0.f;
                float vy0A = ((unsigned)y0A < (unsigned)hw) ? 1.f : 0.f;
                float vy1A = ((unsigned)y1A < (unsigned)hw) ? 1.f : 0.f;
                int cx0A = min(max(x0A, 0), hw - 1), cx1A = min(max(x1A, 0), hw - 1);
                int cy0A = min(max(y0A, 0), hw - 1), cy1A = min(max(y1A, 0), hw - 1);
                int r0A = cy0A << sh, r1A = cy1A << sh;

                // ---- coords B ----
                float xB = lxB[p] * fhw - 0.5f, yB = lyB[p] * fhw - 0.5f;
                float xfB = floorf(xB), yfB = floorf(yB);
                float fxB = xB - xfB, fyB = yB - yfB;
                int x0B = (int)xfB, y0B = (int)yfB;
                int x1B = x0B + 1, y1B = y0B + 1;
                float vx0B = ((unsigned)x0B < (unsigned)hw) ? 1.f : 0.f;
                float vx1B = ((unsigned)x1B < (unsigned)hw) ? 1.f : 0.f;
                float vy0B = ((unsigned)y0B < (unsigned)hw) ? 1.f : 0.f;
                float vy1B = ((unsigned)y1B < (unsigned)hw) ? 1.f : 0.f;
                int cx0B = min(max(x0B, 0), hw - 1), cx1B = min(max(x1B, 0), hw - 1);
                int cy0B = min(max(y0B, 0), hw - 1), cy1B = min(max(y1B, 0), hw - 1);
                int r0B = cy0B << sh, r1B = cy1B << sh;

                union U { uint4 u; __half2 h2[4]; };
                U a00, a01, a10, a11, b00, b01, b10, b11;

                if (l < 2) {
                    const int start = lvl_start[l];
                    unsigned oA00 = ((unsigned)(start + r0A + cx0A) << 6) + coff;
                    unsigned oA01 = ((unsigned)(start + r0A + cx1A) << 6) + coff;
                    unsigned oA10 = ((unsigned)(start + r1A + cx0A) << 6) + coff;
                    unsigned oA11 = ((unsigned)(start + r1A + cx1A) << 6) + coff;
                    unsigned oB00 = ((unsigned)(start + r0B + cx0B) << 6) + coff;
                    unsigned oB01 = ((unsigned)(start + r0B + cx1B) << 6) + coff;
                    unsigned oB10 = ((unsigned)(start + r1B + cx0B) << 6) + coff;
                    unsigned oB11 = ((unsigned)(start + r1B + cx1B) << 6) + coff;
                    a00.u = *(const uint4*)(vb + oA00);
                    a01.u = *(const uint4*)(vb + oA01);
                    a10.u = *(const uint4*)(vb + oA10);
                    a11.u = *(const uint4*)(vb + oA11);
                    b00.u = *(const uint4*)(vb + oB00);
                    b01.u = *(const uint4*)(vb + oB01);
                    b10.u = *(const uint4*)(vb + oB10);
                    b11.u = *(const uint4*)(vb + oB11);
                } else {
                    const int lstart = lvl_lstart[l];
                    unsigned oA00 = ((unsigned)(lstart + r0A + cx0A) << 6) + coff;
                    unsigned oA01 = ((unsigned)(lstart + r0A + cx1A) << 6) + coff;
                    unsigned oA10 = ((unsigned)(lstart + r1A + cx0A) << 6) + coff;
                    unsigned oA11 = ((unsigned)(lstart + r1A + cx1A) << 6) + coff;
                    unsigned oB00 = ((unsigned)(lstart + r0B + cx0B) << 6) + coff;
                    unsigned oB01 = ((unsigned)(lstart + r0B + cx1B) << 6) + coff;
                    unsigned oB10 = ((unsigned)(lstart + r1B + cx0B) << 6) + coff;
                    unsigned oB11 = ((unsigned)(lstart + r1B + cx1B) << 6) + coff;
                    a00.u = *(const uint4*)(smem + oA00);
                    a01.u = *(const uint4*)(smem + oA01);
                    a10.u = *(const uint4*)(smem + oA10);
                    a11.u = *(const uint4*)(smem + oA11);
                    b00.u = *(const uint4*)(smem + oB00);
                    b01.u = *(const uint4*)(smem + oB01);
                    b10.u = *(const uint4*)(smem + oB10);
                    b11.u = *(const uint4*)(smem + oB11);
                }

                float wgtA = wlA[p];
                float wA00 = (1.f - fxA) * (1.f - fyA) * wgtA * vx0A * vy0A;
                float wA01 = fxA * (1.f - fyA) * wgtA * vx1A * vy0A;
                float wA10 = (1.f - fxA) * fyA * wgtA * vx0A * vy1A;
                float wA11 = fxA * fyA * wgtA * vx1A * vy1A;
                float wgtB = wlB[p];
                float wB00 = (1.f - fxB) * (1.f - fyB) * wgtB * vx0B * vy0B;
                float wB01 = fxB * (1.f - fyB) * wgtB * vx1B * vy0B;
                float wB10 = (1.f - fxB) * fyB * wgtB * vx0B * vy1B;
                float wB11 = fxB * fyB * wgtB * vx1B * vy1B;

#pragma unroll
                for (int j = 0; j < 4; ++j) {
                    float2 fA00 = __half22float2(a00.h2[j]);
                    float2 fA01 = __half22float2(a01.h2[j]);
                    float2 fA10 = __half22float2(a10.h2[j]);
                    float2 fA11 = __half22float2(a11.h2[j]);
                    accA[j].x += wA00 * fA00.x + wA01 * fA01.x + wA10 * fA10.x + wA11 * fA11.x;
                    accA[j].y += wA00 * fA00.y + wA01 * fA01.y + wA10 * fA10.y + wA11 * fA11.y;
                    float2 fB00 = __half22float2(b00.h2[j]);
                    float2 fB01 = __half22float2(b01.h2[j]);
                    float2 fB10 = __half22float2(b10.h2[j]);
                    float2 fB11 = __half22float2(b11.h2[j]);
                    accB[j].x += wB00 * fB00.x + wB01 * fB01.x + wB10 * fB10.x + wB11 * fB11.x;
                    accB[j].y += wB00 * fB00.y + wB01 * fB01.y + wB10 * fB10.y + wB11 * fB11.y;
                }
            }
        }

        if (valid) {
            float4* opA = (float4*)out + bqhA * (D / 4) + lane * 2;
            opA[0] = make_float4(accA[0].x, accA[0].y, accA[1].x, accA[1].y);
            opA[1] = make_float4(accA[2].x, accA[2].y, accA[3].x, accA[3].y);
            float4* opB = (float4*)out + bqhB * (D / 4) + lane * 2;
            opB[0] = make_float4(accB[0].x, accB[0].y, accB[1].x, accB[1].y);
            opB[1] = make_float4(accB[2].x, accB[2].y, accB[3].x, accB[3].y);
        }
    }
}

// ---------------- round-5 fp16 kernel (fallback if big-LDS attr fails) ------
__global__ __launch_bounds__(256) void msda_fwd_fp16_kernel(
    const __half* __restrict__ vw, const float* __restrict__ loc,
    const float* __restrict__ aw, float* __restrict__ out)
{
    constexpr int H = MSDA_H, D = MSDA_D, L = MSDA_L, P = MSDA_P;
    constexpr int S = MSDA_S, Q = MSDA_Q;
    const int lvl_sh[4]    = {7, 6, 5, 4};
    const int lvl_start[4] = {0, 16384, 20480, 21504};

    int i = blockIdx.x;
    int h = i & 7;
    int r = i >> 3;
    int b = r / MSDA_QBLK16;
    int qb = r - b * MSDA_QBLK16;

    int q = qb * 64 + (threadIdx.x >> 2);
    if (q >= Q) return;
    const int lane = threadIdx.x & 3;
    const unsigned coff = (unsigned)lane * 16;

    const size_t bqh = ((size_t)b * Q + q) * H + h;
    const float4* lp4 = (const float4*)(loc + bqh * (L * P * 2));
    const float4* wp4 = (const float4*)(aw  + bqh * (L * P));
    const char* vb = (const char*)(vw + (size_t)(b * H + h) * S * D);

    float2 acc[4] = {{0.f,0.f},{0.f,0.f},{0.f,0.f},{0.f,0.f}};

#pragma unroll
    for (int l = 0; l < L; ++l) {
        const int sh = lvl_sh[l];
        const int hw = 1 << sh;
        const float fhw = (float)hw;
        const int start = lvl_start[l];

        float4 la = lp4[2 * l + 0];
        float4 lb = lp4[2 * l + 1];
        float4 wv = wp4[l];
        float lx[4] = {la.x, la.z, lb.x, lb.z};
        float ly[4] = {la.y, la.w, lb.y, lb.w};
        float wl[4] = {wv.x, wv.y, wv.z, wv.w};

#pragma unroll
        for (int p = 0; p < P; ++p) {
            float x = lx[p] * fhw - 0.5f;
            float y = ly[p] * fhw - 0.5f;
            float xf = floorf(x), yf = floorf(y);
            float fx = x - xf, fy = y - yf;
            int x0 = (int)xf, y0 = (int)yf;
            int x1 = x0 + 1, y1 = y0 + 1;

            float vx0 = ((unsigned)x0 < (unsigned)hw) ? 1.f : 0.f;
            float vx1 = ((unsigned)x1 < (unsigned)hw) ? 1.f : 0.f;
            float vy0 = ((unsigned)y0 < (unsigned)hw) ? 1.f : 0.f;
            float vy1 = ((unsigned)y1 < (unsigned)hw) ? 1.f : 0.f;

            int cx0 = min(max(x0, 0), hw - 1);
            int cx1 = min(max(x1, 0), hw - 1);
            int cy0 = min(max(y0, 0), hw - 1);
            int cy1 = min(max(y1, 0), hw - 1);

            int r0 = start + (cy0 << sh);
            int r1 = start + (cy1 << sh);
            unsigned o00 = ((unsigned)(r0 + cx0) << 6) + coff;
            unsigned o01 = ((unsigned)(r0 + cx1) << 6) + coff;
            unsigned o10 = ((unsigned)(r1 + cx0) << 6) + coff;
            unsigned o11 = ((unsigned)(r1 + cx1) << 6) + coff;

            union U { uint4 u; __half2 h2[4]; };
            U u00, u01, u10, u11;
            u00.u = *(const uint4*)(vb + o00);
            u01.u = *(const uint4*)(vb + o01);
            u10.u = *(const uint4*)(vb + o10);
            u11.u = *(const uint4*)(vb + o11);

            float wgt = wl[p];
            float w00 = (1.f - fx) * (1.f - fy) * wgt * vx0 * vy0;
            float w01 = fx * (1.f - fy) * wgt * vx1 * vy0;
            float w10 = (1.f - fx) * fy * wgt * vx0 * vy1;
            float w11 = fx * fy * wgt * vx1 * vy1;

#pragma unroll
            for (int j = 0; j < 4; ++j) {
                float2 f00 = __half22float2(u00.h2[j]);
                float2 f01 = __half22float2(u01.h2[j]);
                float2 f10 = __half22float2(u10.h2[j]);
                float2 f11 = __half22float2(u11.h2[j]);
                acc[j].x += w00 * f00.x + w01 * f01.x + w10 * f10.x + w11 * f11.x;
                acc[j].y += w00 * f00.y + w01 * f01.y + w10 * f10.y + w11 * f11.y;
            }
        }
    }

    float4* op = (float4*)out + bqh * (D / 4) + lane * 2;
    op[0] = make_float4(acc[0].x, acc[0].y, acc[1].x, acc[1].y);
    op[1] = make_float4(acc[2].x, acc[2].y, acc[3].x, acc[3].y);
}

// ---------------- fp32 fallback (round-4 kernel) ----------------
__global__ __launch_bounds__(256, 4) void msda_fwd_fp32_kernel(
    const float* __restrict__ value, const float* __restrict__ loc,
    const float* __restrict__ aw, float* __restrict__ out)
{
    constexpr int H = MSDA_H, D = MSDA_D, L = MSDA_L, P = MSDA_P;
    constexpr int S = MSDA_S, Q = MSDA_Q;
    const int lvl_sh[4]    = {7, 6, 5, 4};
    const int lvl_start[4] = {0, 16384, 20480, 21504};

    int i = blockIdx.x;
    int h = i & 7;
    int r = i >> 3;
    int b = r / MSDA_QBLK32;
    int qb = r - b * MSDA_QBLK32;

    int q = qb * 32 + (threadIdx.x >> 3);
    if (q >= Q) return;
    const unsigned coff = (threadIdx.x & 7) * 16;

    const size_t bqh = ((size_t)b * Q + q) * H + h;
    const float4* lp4 = (const float4*)(loc + bqh * (L * P * 2));
    const float4* wp4 = (const float4*)(aw  + bqh * (L * P));
    const char* vb = (const char*)(value + ((size_t)b * S * H + h) * D);

    float4 acc = {0.f, 0.f, 0.f, 0.f};

#pragma unroll
    for (int l = 0; l < L; ++l) {
        const int sh = lvl_sh[l];
        const int hw = 1 << sh;
        const float fhw = (float)hw;
        const int start = lvl_start[l];

        float4 la = lp4[2 * l + 0];
        float4 lb = lp4[2 * l + 1];
        float4 wv = wp4[l];
        float lx[4] = {la.x, la.z, lb.x, lb.z};
        float ly[4] = {la.y, la.w, lb.y, lb.w};
        float wl[4] = {wv.x, wv.y, wv.z, wv.w};

#pragma unroll
        for (int p = 0; p < P; ++p) {
            float x = lx[p] * fhw - 0.5f;
            float y = ly[p] * fhw - 0.5f;
            float xf = floorf(x), yf = floorf(y);
            float fx = x - xf, fy = y - yf;
            int x0 = (int)xf, y0 = (int)yf;
            int x1 = x0 + 1, y1 = y0 + 1;

            float vx0 = ((unsigned)x0 < (unsigned)hw) ? 1.f : 0.f;
            float vx1 = ((unsigned)x1 < (unsigned)hw) ? 1.f : 0.f;
            float vy0 = ((unsigned)y0 < (unsigned)hw) ? 1.f : 0.f;
            float vy1 = ((unsigned)y1 < (unsigned)hw) ? 1.f : 0.f;

            int cx0 = min(max(x0, 0), hw - 1);
            int cx1 = min(max(x1, 0), hw - 1);
            int cy0 = min(max(y0, 0), hw - 1);
            int cy1 = min(max(y1, 0), hw - 1);

            float wgt = wl[p];
            float w00 = (1.f - fx) * (1.f - fy) * wgt * vx0 * vy0;
            float w01 = fx * (1.f - fy) * wgt * vx1 * vy0;
            float w10 = (1.f - fx) * fy * wgt * vx0 * vy1;
            float w11 = fx * fy * wgt * vx1 * vy1;

            int r0 = start + (cy0 << sh);
            int r1 = start + (cy1 << sh);
            unsigned o00 = ((unsigned)(r0 + cx0) << 10) + coff;
            unsigned o01 = ((unsigned)(r0 + cx1) << 10) + coff;
            unsigned o10 = ((unsigned)(r1 + cx0) << 10) + coff;
            unsigned o11 = ((unsigned)(r1 + cx1) << 10) + coff;

            float4 v00 = *(const float4*)(vb + o00);
            float4 v01 = *(const float4*)(vb + o01);
            float4 v10 = *(const float4*)(vb + o10);
            float4 v11 = *(const float4*)(vb + o11);

            acc.x += w00 * v00.x + w01 * v01.x + w10 * v10.x + w11 * v11.x;
            acc.y += w00 * v00.y + w01 * v01.y + w10 * v10.y + w11 * v11.y;
            acc.z += w00 * v00.z + w01 * v01.z + w10 * v10.z + w11 * v11.z;
            acc.w += w00 * v00.w + w01 * v01.w + w10 * v10.w + w11 * v11.w;
        }
    }

    ((float4*)out)[bqh * (D / 4) + (threadIdx.x & 7)] = acc;
}

extern "C" void kernel_launch(void* const* d_in, const int* in_sizes, int n_in,
                              void* d_out, int out_size, void* d_ws, size_t ws_size,
                              hipStream_t stream) {
    const float* value = (const float*)d_in[0];
    const float* loc = (const float*)d_in[3];
    const float* aw  = (const float*)d_in[4];
    float* out = (float*)d_out;

    // one-time: allow 80KB dynamic LDS on the LDS-path kernel
    static int lds_ok = -1;
    if (lds_ok < 0) {
        hipError_t e = hipFuncSetAttribute(
            reinterpret_cast<const void*>(msda_fwd_lds_kernel),
            hipFuncAttributeMaxDynamicSharedMemorySize, MSDA_LDS_BYTES);
        lds_ok = (e == hipSuccess) ? 1 : 0;
    }

    const size_t need = (size_t)MSDA_B * MSDA_H * MSDA_S * MSDA_D * sizeof(__half);
    if (ws_size >= need) {
        __half* vw = (__half*)d_ws;
        msda_convert_kernel<<<(MSDA_B * MSDA_S * MSDA_H * MSDA_D / 4 + 255) / 256,
                              256, 0, stream>>>(value, vw);
        if (lds_ok) {
            const int grid = MSDA_B * MSDA_H * MSDA_NB;   // 256 = 1 block/CU
            msda_fwd_lds_kernel<<<grid, 512, MSDA_LDS_BYTES, stream>>>(vw, loc, aw, out);
        } else {
            const int grid = 8 * MSDA_B * MSDA_QBLK16;    // 5024
            msda_fwd_fp16_kernel<<<grid, 256, 0, stream>>>(vw, loc, aw, out);
        }
    } else {
        const int grid = 8 * MSDA_B * MSDA_QBLK32;        // 10016
        msda_fwd_fp32_kernel<<<grid, 256, 0, stream>>>(value, loc, aw, out);
    }
}

// Round 9
// 281.213 us; speedup vs baseline: 1.7025x; 1.7025x over previous
//
#include <hip/hip_runtime.h>
#include <hip/hip_fp16.h>

// MultiScaleDeformableAttention forward (Deformable-DETR), fp32 in/out.
// B=4, S=21760, H=8, D=32, Q=10000, L=4, P=4.
// Levels (static): (128,128),(64,64),(32,32),(16,16); starts 0,16384,20480,21504.
//
// Round 14. Round-13 post-mortem: (512,1) does NOT lift the VGPR cap --
// 512-thread blocks are capped at 128 VGPRs period ((512,1)->128 measured,
// dual-query needed ~200 -> 420MB spill writes -> 319us). Revert dual-query.
// Cost model: L0/L1 gathers ~9.2us/M (L2/L3-latency-bound, ~107 cyc/instr
// => MLP~4: compiler only keeps one point's 4 loads in flight).
// This round: POINT-PAIRING. Per level, compute offsets for 2 points,
// issue all 8 corner loads back-to-back, then weights+FMA. In-flight data
// 32 VGPR (vs 64 for dual-query) -> fits the 128 cap; MLP 4->8.
// Plus grid=256 (1 blk/CU, single round, staging halved vs 512 blocks).
// Measured launch_bounds map: (512,2)->120 ok, (512,1)->128, (512,4)->64
// spill, (1024,1)->64 spill.
// Fallbacks: no big-LDS attr -> round-5 fp16 kernel; small ws -> fp32 kernel.

#define MSDA_B 4
#define MSDA_Q 10000
#define MSDA_H 8
#define MSDA_D 32
#define MSDA_L 4
#define MSDA_P 4
#define MSDA_S 21760

#define MSDA_QBLK16 157   // ceil(10000/64) q-blocks per (b,h) (round-5 fp16 path)
#define MSDA_QBLK32 313   // ceil(10000/32) (fp32 fallback path)

#define MSDA_NB 8         // q-chunks per (b,h) slice (LDS path)
#define MSDA_QPC 1250     // queries per chunk; 8*1250 = 10000 exactly
#define MSDA_LDS_BYTES 81920  // levels 2+3: 1280 pixels * 64 B

// ---------------- pre-pass: fp32 [B,S,H,D] -> fp16 [B,H,S,D] ----------------
__global__ __launch_bounds__(256) void msda_convert_kernel(
    const float* __restrict__ value, __half* __restrict__ vw)
{
    int o4 = blockIdx.x * 256 + threadIdx.x;      // index of 4 halves in output
    int d4 = o4 & 7;                               // D/4 = 8
    int rest = o4 >> 3;                            // (b*H + h)*S + s
    int s = rest % MSDA_S;
    int bh = rest / MSDA_S;
    int b = bh >> 3, h = bh & 7;
    float4 v = *(const float4*)(value +
        (((size_t)b * MSDA_S + s) * MSDA_H + h) * MSDA_D + 4 * d4);
    union { __half2 h2[2]; uint2 u; } pk;
    pk.h2[0] = __floats2half2_rn(v.x, v.y);
    pk.h2[1] = __floats2half2_rn(v.z, v.w);
    ((uint2*)vw)[o4] = pk.u;
}

// ------- main kernel (fp16 gather + LDS levels 2,3; point-paired loads) -----
__global__ __launch_bounds__(512, 2) void msda_fwd_lds_kernel(
    const __half* __restrict__ vw,     // [B,H,S,D] fp16
    const float* __restrict__ loc,     // [B,Q,H,L,P,2]
    const float* __restrict__ aw,      // [B,Q,H,L,P]
    float* __restrict__ out)           // [B,Q,H,D]
{
    constexpr int H = MSDA_H, D = MSDA_D, L = MSDA_L, P = MSDA_P;
    constexpr int Q = MSDA_Q, S = MSDA_S;
    const int lvl_sh[4]     = {7, 6, 5, 4};
    const int lvl_start[4]  = {0, 16384, 20480, 21504};
    const int lvl_lstart[4] = {0, 0, 0, 1024};   // local pixel base in LDS (l>=2)

    extern __shared__ char smem[];

    // XCD-affine: blockIdx%8 = XCD = head. 256 blocks = 1 per CU.
    int i = blockIdx.x;
    int h = i & 7;
    int r = i >> 3;                     // [0,32)
    int qc = r & (MSDA_NB - 1);         // [0,8)
    int b = r >> 3;                     // [0,4)

    const size_t slice = (size_t)(b * H + h) * S * D;   // in halves

    // ---- stage levels 2+3 (pixels 20480..21759, 80KB contiguous) ----
    {
        const uint4* src = (const uint4*)(vw + slice + (size_t)20480 * D);
        uint4* dst = (uint4*)smem;
#pragma unroll
        for (int k = 0; k < 10; ++k)                     // 10*512 = 5120 uint4
            dst[threadIdx.x + 512 * k] = src[threadIdx.x + 512 * k];
    }
    __syncthreads();

    const int lane = threadIdx.x & 3;
    const unsigned coff = (unsigned)lane * 16;    // 16B = 8 halves = d[8k..8k+7]
    const int qsub = threadIdx.x >> 2;            // quad id [0,128)
    const char* vb = (const char*)(vw + slice);

    const int qcbase = qc * MSDA_QPC;

    for (int it = 0; it < 10; ++it) {
        int off = it * 128 + qsub;                // [0,1280)
        if (off >= MSDA_QPC) break;               // per-quad uniform; no barriers
        int q = qcbase + off;

        const size_t bqh = ((size_t)b * Q + q) * H + h;
        const float4* lp4 = (const float4*)(loc + bqh * (L * P * 2));
        const float4* wp4 = (const float4*)(aw  + bqh * (L * P));

        float2 acc[4] = {{0.f,0.f},{0.f,0.f},{0.f,0.f},{0.f,0.f}};

#pragma unroll
        for (int l = 0; l < L; ++l) {
            const int sh = lvl_sh[l];
            const int hw = 1 << sh;
            const float fhw = (float)hw;

            float4 la = lp4[2 * l + 0];
            float4 lb = lp4[2 * l + 1];
            float4 wv = wp4[l];
            float lx[4] = {la.x, la.z, lb.x, lb.z};
            float ly[4] = {la.y, la.w, lb.y, lb.w};
            float wl[4] = {wv.x, wv.y, wv.z, wv.w};

#pragma unroll
            for (int p = 0; p < P; p += 2) {
                // ---- coords for point p (suffix 0) and p+1 (suffix 1) ----
                float x0c = lx[p] * fhw - 0.5f,     y0c = ly[p] * fhw - 0.5f;
                float x1c = lx[p + 1] * fhw - 0.5f, y1c = ly[p + 1] * fhw - 0.5f;

                float xf0 = floorf(x0c), yf0 = floorf(y0c);
                float xf1 = floorf(x1c), yf1 = floorf(y1c);
                float fx0 = x0c - xf0, fy0 = y0c - yf0;
                float fx1 = x1c - xf1, fy1 = y1c - yf1;

                int ax0 = (int)xf0, ay0 = (int)yf0;
                int ax1 = ax0 + 1,  ay1 = ay0 + 1;
                int bx0 = (int)xf1, by0 = (int)yf1;
                int bx1 = bx0 + 1,  by1 = by0 + 1;

                float avx0 = ((unsigned)ax0 < (unsigned)hw) ? 1.f : 0.f;
                float avx1 = ((unsigned)ax1 < (unsigned)hw) ? 1.f : 0.f;
                float avy0 = ((unsigned)ay0 < (unsigned)hw) ? 1.f : 0.f;
                float avy1 = ((unsigned)ay1 < (unsigned)hw) ? 1.f : 0.f;
                float bvx0 = ((unsigned)bx0 < (unsigned)hw) ? 1.f : 0.f;
                float bvx1 = ((unsigned)bx1 < (unsigned)hw) ? 1.f : 0.f;
                float bvy0 = ((unsigned)by0 < (unsigned)hw) ? 1.f : 0.f;
                float bvy1 = ((unsigned)by1 < (unsigned)hw) ? 1.f : 0.f;

                int acx0 = min(max(ax0, 0), hw - 1), acx1 = min(max(ax1, 0), hw - 1);
                int acy0 = min(max(ay0, 0), hw - 1), acy1 = min(max(ay1, 0), hw - 1);
                int bcx0 = min(max(bx0, 0), hw - 1), bcx1 = min(max(bx1, 0), hw - 1);
                int bcy0 = min(max(by0, 0), hw - 1), bcy1 = min(max(by1, 0), hw - 1);

                int ar0 = acy0 << sh, ar1 = acy1 << sh;
                int br0 = bcy0 << sh, br1 = bcy1 << sh;

                // ---- 8 offsets, then 8 loads issued back-to-back ----
                union U { uint4 u; __half2 h2[4]; };
                U ua00, ua01, ua10, ua11, ub00, ub01, ub10, ub11;

                if (l < 2) {
                    const int start = lvl_start[l];
                    unsigned oa00 = ((unsigned)(start + ar0 + acx0) << 6) + coff;
                    unsigned oa01 = ((unsigned)(start + ar0 + acx1) << 6) + coff;
                    unsigned oa10 = ((unsigned)(start + ar1 + acx0) << 6) + coff;
                    unsigned oa11 = ((unsigned)(start + ar1 + acx1) << 6) + coff;
                    unsigned ob00 = ((unsigned)(start + br0 + bcx0) << 6) + coff;
                    unsigned ob01 = ((unsigned)(start + br0 + bcx1) << 6) + coff;
                    unsigned ob10 = ((unsigned)(start + br1 + bcx0) << 6) + coff;
                    unsigned ob11 = ((unsigned)(start + br1 + bcx1) << 6) + coff;
                    ua00.u = *(const uint4*)(vb + oa00);
                    ua01.u = *(const uint4*)(vb + oa01);
                    ua10.u = *(const uint4*)(vb + oa10);
                    ua11.u = *(const uint4*)(vb + oa11);
                    ub00.u = *(const uint4*)(vb + ob00);
                    ub01.u = *(const uint4*)(vb + ob01);
                    ub10.u = *(const uint4*)(vb + ob10);
                    ub11.u = *(const uint4*)(vb + ob11);
                } else {
                    const int lstart = lvl_lstart[l];
                    unsigned oa00 = ((unsigned)(lstart + ar0 + acx0) << 6) + coff;
                    unsigned oa01 = ((unsigned)(lstart + ar0 + acx1) << 6) + coff;
                    unsigned oa10 = ((unsigned)(lstart + ar1 + acx0) << 6) + coff;
                    unsigned oa11 = ((unsigned)(lstart + ar1 + acx1) << 6) + coff;
                    unsigned ob00 = ((unsigned)(lstart + br0 + bcx0) << 6) + coff;
                    unsigned ob01 = ((unsigned)(lstart + br0 + bcx1) << 6) + coff;
                    unsigned ob10 = ((unsigned)(lstart + br1 + bcx0) << 6) + coff;
                    unsigned ob11 = ((unsigned)(lstart + br1 + bcx1) << 6) + coff;
                    ua00.u = *(const uint4*)(smem + oa00);
                    ua01.u = *(const uint4*)(smem + oa01);
                    ua10.u = *(const uint4*)(smem + oa10);
                    ua11.u = *(const uint4*)(smem + oa11);
                    ub00.u = *(const uint4*)(smem + ob00);
                    ub01.u = *(const uint4*)(smem + ob01);
                    ub10.u = *(const uint4*)(smem + ob10);
                    ub11.u = *(const uint4*)(smem + ob11);
                }

                // ---- weights (computed while loads are in flight) ----
                float wgta = wl[p];
                float wa00 = (1.f - fx0) * (1.f - fy0) * wgta * avx0 * avy0;
                float wa01 = fx0 * (1.f - fy0) * wgta * avx1 * avy0;
                float wa10 = (1.f - fx0) * fy0 * wgta * avx0 * avy1;
                float wa11 = fx0 * fy0 * wgta * avx1 * avy1;
                float wgtb = wl[p + 1];
                float wb00 = (1.f - fx1) * (1.f - fy1) * wgtb * bvx0 * bvy0;
                float wb01 = fx1 * (1.f - fy1) * wgtb * bvx1 * bvy0;
                float wb10 = (1.f - fx1) * fy1 * wgtb * bvx0 * bvy1;
                float wb11 = fx1 * fy1 * wgtb * bvx1 * bvy1;

#pragma unroll
                for (int j = 0; j < 4; ++j) {
                    float2 fa00 = __half22float2(ua00.h2[j]);
                    float2 fa01 = __half22float2(ua01.h2[j]);
                    float2 fa10 = __half22float2(ua10.h2[j]);
                    float2 fa11 = __half22float2(ua11.h2[j]);
                    acc[j].x += wa00 * fa00.x + wa01 * fa01.x + wa10 * fa10.x + wa11 * fa11.x;
                    acc[j].y += wa00 * fa00.y + wa01 * fa01.y + wa10 * fa10.y + wa11 * fa11.y;
                    float2 fb00 = __half22float2(ub00.h2[j]);
                    float2 fb01 = __half22float2(ub01.h2[j]);
                    float2 fb10 = __half22float2(ub10.h2[j]);
                    float2 fb11 = __half22float2(ub11.h2[j]);
                    acc[j].x += wb00 * fb00.x + wb01 * fb01.x + wb10 * fb10.x + wb11 * fb11.x;
                    acc[j].y += wb00 * fb00.y + wb01 * fb01.y + wb10 * fb10.y + wb11 * fb11.y;
                }
            }
        }

        // lane owns d[8*lane .. 8*lane+7] -> float4 chunks 2*lane, 2*lane+1
        float4* op = (float4*)out + bqh * (D / 4) + lane * 2;
        op[0] = make_float4(acc[0].x, acc[0].y, acc[1].x, acc[1].y);
        op[1] = make_float4(acc[2].x, acc[2].y, acc[3].x, acc[3].y);
    }
}

// ---------------- round-5 fp16 kernel (fallback if big-LDS attr fails) ------
__global__ __launch_bounds__(256) void msda_fwd_fp16_kernel(
    const __half* __restrict__ vw, const float* __restrict__ loc,
    const float* __restrict__ aw, float* __restrict__ out)
{
    constexpr int H = MSDA_H, D = MSDA_D, L = MSDA_L, P = MSDA_P;
    constexpr int S = MSDA_S, Q = MSDA_Q;
    const int lvl_sh[4]    = {7, 6, 5, 4};
    const int lvl_start[4] = {0, 16384, 20480, 21504};

    int i = blockIdx.x;
    int h = i & 7;
    int r = i >> 3;
    int b = r / MSDA_QBLK16;
    int qb = r - b * MSDA_QBLK16;

    int q = qb * 64 + (threadIdx.x >> 2);
    if (q >= Q) return;
    const int lane = threadIdx.x & 3;
    const unsigned coff = (unsigned)lane * 16;

    const size_t bqh = ((size_t)b * Q + q) * H + h;
    const float4* lp4 = (const float4*)(loc + bqh * (L * P * 2));
    const float4* wp4 = (const float4*)(aw  + bqh * (L * P));
    const char* vb = (const char*)(vw + (size_t)(b * H + h) * S * D);

    float2 acc[4] = {{0.f,0.f},{0.f,0.f},{0.f,0.f},{0.f,0.f}};

#pragma unroll
    for (int l = 0; l < L; ++l) {
        const int sh = lvl_sh[l];
        const int hw = 1 << sh;
        const float fhw = (float)hw;
        const int start = lvl_start[l];

        float4 la = lp4[2 * l + 0];
        float4 lb = lp4[2 * l + 1];
        float4 wv = wp4[l];
        float lx[4] = {la.x, la.z, lb.x, lb.z};
        float ly[4] = {la.y, la.w, lb.y, lb.w};
        float wl[4] = {wv.x, wv.y, wv.z, wv.w};

#pragma unroll
        for (int p = 0; p < P; ++p) {
            float x = lx[p] * fhw - 0.5f;
            float y = ly[p] * fhw - 0.5f;
            float xf = floorf(x), yf = floorf(y);
            float fx = x - xf, fy = y - yf;
            int x0 = (int)xf, y0 = (int)yf;
            int x1 = x0 + 1, y1 = y0 + 1;

            float vx0 = ((unsigned)x0 < (unsigned)hw) ? 1.f : 0.f;
            float vx1 = ((unsigned)x1 < (unsigned)hw) ? 1.f : 0.f;
            float vy0 = ((unsigned)y0 < (unsigned)hw) ? 1.f : 0.f;
            float vy1 = ((unsigned)y1 < (unsigned)hw) ? 1.f : 0.f;

            int cx0 = min(max(x0, 0), hw - 1);
            int cx1 = min(max(x1, 0), hw - 1);
            int cy0 = min(max(y0, 0), hw - 1);
            int cy1 = min(max(y1, 0), hw - 1);

            int r0 = start + (cy0 << sh);
            int r1 = start + (cy1 << sh);
            unsigned o00 = ((unsigned)(r0 + cx0) << 6) + coff;
            unsigned o01 = ((unsigned)(r0 + cx1) << 6) + coff;
            unsigned o10 = ((unsigned)(r1 + cx0) << 6) + coff;
            unsigned o11 = ((unsigned)(r1 + cx1) << 6) + coff;

            union U { uint4 u; __half2 h2[4]; };
            U u00, u01, u10, u11;
            u00.u = *(const uint4*)(vb + o00);
            u01.u = *(const uint4*)(vb + o01);
            u10.u = *(const uint4*)(vb + o10);
            u11.u = *(const uint4*)(vb + o11);

            float wgt = wl[p];
            float w00 = (1.f - fx) * (1.f - fy) * wgt * vx0 * vy0;
            float w01 = fx * (1.f - fy) * wgt * vx1 * vy0;
            float w10 = (1.f - fx) * fy * wgt * vx0 * vy1;
            float w11 = fx * fy * wgt * vx1 * vy1;

#pragma unroll
            for (int j = 0; j < 4; ++j) {
                float2 f00 = __half22float2(u00.h2[j]);
                float2 f01 = __half22float2(u01.h2[j]);
                float2 f10 = __half22float2(u10.h2[j]);
                float2 f11 = __half22float2(u11.h2[j]);
                acc[j].x += w00 * f00.x + w01 * f01.x + w10 * f10.x + w11 * f11.x;
                acc[j].y += w00 * f00.y + w01 * f01.y + w10 * f10.y + w11 * f11.y;
            }
        }
    }

    float4* op = (float4*)out + bqh * (D / 4) + lane * 2;
    op[0] = make_float4(acc[0].x, acc[0].y, acc[1].x, acc[1].y);
    op[1] = make_float4(acc[2].x, acc[2].y, acc[3].x, acc[3].y);
}

// ---------------- fp32 fallback (round-4 kernel) ----------------
__global__ __launch_bounds__(256, 4) void msda_fwd_fp32_kernel(
    const float* __restrict__ value, const float* __restrict__ loc,
    const float* __restrict__ aw, float* __restrict__ out)
{
    constexpr int H = MSDA_H, D = MSDA_D, L = MSDA_L, P = MSDA_P;
    constexpr int S = MSDA_S, Q = MSDA_Q;
    const int lvl_sh[4]    = {7, 6, 5, 4};
    const int lvl_start[4] = {0, 16384, 20480, 21504};

    int i = blockIdx.x;
    int h = i & 7;
    int r = i >> 3;
    int b = r / MSDA_QBLK32;
    int qb = r - b * MSDA_QBLK32;

    int q = qb * 32 + (threadIdx.x >> 3);
    if (q >= Q) return;
    const unsigned coff = (threadIdx.x & 7) * 16;

    const size_t bqh = ((size_t)b * Q + q) * H + h;
    const float4* lp4 = (const float4*)(loc + bqh * (L * P * 2));
    const float4* wp4 = (const float4*)(aw  + bqh * (L * P));
    const char* vb = (const char*)(value + ((size_t)b * S * H + h) * D);

    float4 acc = {0.f, 0.f, 0.f, 0.f};

#pragma unroll
    for (int l = 0; l < L; ++l) {
        const int sh = lvl_sh[l];
        const int hw = 1 << sh;
        const float fhw = (float)hw;
        const int start = lvl_start[l];

        float4 la = lp4[2 * l + 0];
        float4 lb = lp4[2 * l + 1];
        float4 wv = wp4[l];
        float lx[4] = {la.x, la.z, lb.x, lb.z};
        float ly[4] = {la.y, la.w, lb.y, lb.w};
        float wl[4] = {wv.x, wv.y, wv.z, wv.w};

#pragma unroll
        for (int p = 0; p < P; ++p) {
            float x = lx[p] * fhw - 0.5f;
            float y = ly[p] * fhw - 0.5f;
            float xf = floorf(x), yf = floorf(y);
            float fx = x - xf, fy = y - yf;
            int x0 = (int)xf, y0 = (int)yf;
            int x1 = x0 + 1, y1 = y0 + 1;

            float vx0 = ((unsigned)x0 < (unsigned)hw) ? 1.f : 0.f;
            float vx1 = ((unsigned)x1 < (unsigned)hw) ? 1.f : 0.f;
            float vy0 = ((unsigned)y0 < (unsigned)hw) ? 1.f : 0.f;
            float vy1 = ((unsigned)y1 < (unsigned)hw) ? 1.f : 0.f;

            int cx0 = min(max(x0, 0), hw - 1);
            int cx1 = min(max(x1, 0), hw - 1);
            int cy0 = min(max(y0, 0), hw - 1);
            int cy1 = min(max(y1, 0), hw - 1);

            float wgt = wl[p];
            float w00 = (1.f - fx) * (1.f - fy) * wgt * vx0 * vy0;
            float w01 = fx * (1.f - fy) * wgt * vx1 * vy0;
            float w10 = (1.f - fx) * fy * wgt * vx0 * vy1;
            float w11 = fx * fy * wgt * vx1 * vy1;

            int r0 = start + (cy0 << sh);
            int r1 = start + (cy1 << sh);
            unsigned o00 = ((unsigned)(r0 + cx0) << 10) + coff;
            unsigned o01 = ((unsigned)(r0 + cx1) << 10) + coff;
            unsigned o10 = ((unsigned)(r1 + cx0) << 10) + coff;
            unsigned o11 = ((unsigned)(r1 + cx1) << 10) + coff;

            float4 v00 = *(const float4*)(vb + o00);
            float4 v01 = *(const float4*)(vb + o01);
            float4 v10 = *(const float4*)(vb + o10);
            float4 v11 = *(const float4*)(vb + o11);

            acc.x += w00 * v00.x + w01 * v01.x + w10 * v10.x + w11 * v11.x;
            acc.y += w00 * v00.y + w01 * v01.y + w10 * v10.y + w11 * v11.y;
            acc.z += w00 * v00.z + w01 * v01.z + w10 * v10.z + w11 * v11.z;
            acc.w += w00 * v00.w + w01 * v01.w + w10 * v10.w + w11 * v11.w;
        }
    }

    ((float4*)out)[bqh * (D / 4) + (threadIdx.x & 7)] = acc;
}

extern "C" void kernel_launch(void* const* d_in, const int* in_sizes, int n_in,
                              void* d_out, int out_size, void* d_ws, size_t ws_size,
                              hipStream_t stream) {
    const float* value = (const float*)d_in[0];
    const float* loc = (const float*)d_in[3];
    const float* aw  = (const float*)d_in[4];
    float* out = (float*)d_out;

    // one-time: allow 80KB dynamic LDS on the LDS-path kernel
    static int lds_ok = -1;
    if (lds_ok < 0) {
        hipError_t e = hipFuncSetAttribute(
            reinterpret_cast<const void*>(msda_fwd_lds_kernel),
            hipFuncAttributeMaxDynamicSharedMemorySize, MSDA_LDS_BYTES);
        lds_ok = (e == hipSuccess) ? 1 : 0;
    }

    const size_t need = (size_t)MSDA_B * MSDA_H * MSDA_S * MSDA_D * sizeof(__half);
    if (ws_size >= need) {
        __half* vw = (__half*)d_ws;
        msda_convert_kernel<<<(MSDA_B * MSDA_S * MSDA_H * MSDA_D / 4 + 255) / 256,
                              256, 0, stream>>>(value, vw);
        if (lds_ok) {
            const int grid = MSDA_B * MSDA_H * MSDA_NB;   // 256 = 1 block/CU
            msda_fwd_lds_kernel<<<grid, 512, MSDA_LDS_BYTES, stream>>>(vw, loc, aw, out);
        } else {
            const int grid = 8 * MSDA_B * MSDA_QBLK16;    // 5024
            msda_fwd_fp16_kernel<<<grid, 256, 0, stream>>>(vw, loc, aw, out);
        }
    } else {
        const int grid = 8 * MSDA_B * MSDA_QBLK32;        // 10016
        msda_fwd_fp32_kernel<<<grid, 256, 0, stream>>>(value, loc, aw, out);
    }
}

// Round 10
// 267.282 us; speedup vs baseline: 1.7913x; 1.0521x over previous
//
#include <hip/hip_runtime.h>
#include <hip/hip_fp16.h>

// MultiScaleDeformableAttention forward (Deformable-DETR), fp32 in/out.
// B=4, S=21760, H=8, D=32, Q=10000, L=4, P=4.
// Levels (static): (128,128),(64,64),(32,32),(16,16); starts 0,16384,20480,21504.
//
// Round 15. Round-14 post-mortem: point-pairing (MLP 4->8) NULL -- 116us vs
// r8's 112, clean counters. Third MLP variant at the same wall => global
// gather term (~40cy/instr, request/segment-bound, bytes-locked) is fixed.
// Cycle model per CU @278K cy: gathers 102K + LDS 42K + VALU ~58K (per-SIMD).
// VALU is dominated by the FMA tail: 4 corners x (8 cvt_f16_f32 + 8 f32 FMA)
// = 64 ops/point. This round: packed-fp16 accumulation (v_pk_fma_f16 via
// __hfma2): per point 4 weight-packs + 16 hfma2 = 20 ops, zero conversions.
// Precision: accumulate fp16 PER LEVEL (<=16 steps, drift <=~4e-3), fold to
// f32 between levels. absmax 0.0078 -> ~0.012, threshold 0.022.
// Structure: r8-proven single-point loop, grid 256 (1 blk/CU), NB=8, (512,2).
// Known toolchain facts: (512,2)->VGPR 120 ok; (512,1)->128; (512,4),(1024,1)
// ->64+spill. Big-dynamic-LDS kernels always 1 WG/CU. LDS pipe cheaper than
// L1-hit global (r11: lv3 via global +21us).
// Fallbacks: no big-LDS attr -> round-5 fp16 kernel; small ws -> fp32 kernel.

#define MSDA_B 4
#define MSDA_Q 10000
#define MSDA_H 8
#define MSDA_D 32
#define MSDA_L 4
#define MSDA_P 4
#define MSDA_S 21760

#define MSDA_QBLK16 157   // ceil(10000/64) q-blocks per (b,h) (round-5 fp16 path)
#define MSDA_QBLK32 313   // ceil(10000/32) (fp32 fallback path)

#define MSDA_NB 8         // q-chunks per (b,h) slice (LDS path)
#define MSDA_QPC 1250     // queries per chunk; 8*1250 = 10000 exactly
#define MSDA_LDS_BYTES 81920  // levels 2+3: 1280 pixels * 64 B

// ---------------- pre-pass: fp32 [B,S,H,D] -> fp16 [B,H,S,D] ----------------
__global__ __launch_bounds__(256) void msda_convert_kernel(
    const float* __restrict__ value, __half* __restrict__ vw)
{
    int o4 = blockIdx.x * 256 + threadIdx.x;      // index of 4 halves in output
    int d4 = o4 & 7;                               // D/4 = 8
    int rest = o4 >> 3;                            // (b*H + h)*S + s
    int s = rest % MSDA_S;
    int bh = rest / MSDA_S;
    int b = bh >> 3, h = bh & 7;
    float4 v = *(const float4*)(value +
        (((size_t)b * MSDA_S + s) * MSDA_H + h) * MSDA_D + 4 * d4);
    union { __half2 h2[2]; uint2 u; } pk;
    pk.h2[0] = __floats2half2_rn(v.x, v.y);
    pk.h2[1] = __floats2half2_rn(v.z, v.w);
    ((uint2*)vw)[o4] = pk.u;
}

// ---- main kernel (fp16 gather + LDS lv2,3; packed-fp16 per-level accum) ----
__global__ __launch_bounds__(512, 2) void msda_fwd_lds_kernel(
    const __half* __restrict__ vw,     // [B,H,S,D] fp16
    const float* __restrict__ loc,     // [B,Q,H,L,P,2]
    const float* __restrict__ aw,      // [B,Q,H,L,P]
    float* __restrict__ out)           // [B,Q,H,D]
{
    constexpr int H = MSDA_H, D = MSDA_D, L = MSDA_L, P = MSDA_P;
    constexpr int Q = MSDA_Q, S = MSDA_S;
    const int lvl_sh[4]     = {7, 6, 5, 4};
    const int lvl_start[4]  = {0, 16384, 20480, 21504};
    const int lvl_lstart[4] = {0, 0, 0, 1024};   // local pixel base in LDS (l>=2)

    extern __shared__ char smem[];

    // XCD-affine: blockIdx%8 = XCD = head. 256 blocks = 1 per CU.
    int i = blockIdx.x;
    int h = i & 7;
    int r = i >> 3;                     // [0,32)
    int qc = r & (MSDA_NB - 1);         // [0,8)
    int b = r >> 3;                     // [0,4)

    const size_t slice = (size_t)(b * H + h) * S * D;   // in halves

    // ---- stage levels 2+3 (pixels 20480..21759, 80KB contiguous) ----
    {
        const uint4* src = (const uint4*)(vw + slice + (size_t)20480 * D);
        uint4* dst = (uint4*)smem;
#pragma unroll
        for (int k = 0; k < 10; ++k)                     // 10*512 = 5120 uint4
            dst[threadIdx.x + 512 * k] = src[threadIdx.x + 512 * k];
    }
    __syncthreads();

    const int lane = threadIdx.x & 3;
    const unsigned coff = (unsigned)lane * 16;    // 16B = 8 halves = d[8k..8k+7]
    const int qsub = threadIdx.x >> 2;            // quad id [0,128)
    const char* vb = (const char*)(vw + slice);

    const int qcbase = qc * MSDA_QPC;

    for (int it = 0; it < 10; ++it) {
        int off = it * 128 + qsub;                // [0,1280)
        if (off >= MSDA_QPC) break;               // per-quad uniform; no barriers
        int q = qcbase + off;

        const size_t bqh = ((size_t)b * Q + q) * H + h;
        const float4* lp4 = (const float4*)(loc + bqh * (L * P * 2));
        const float4* wp4 = (const float4*)(aw  + bqh * (L * P));

        float2 acc[4] = {{0.f,0.f},{0.f,0.f},{0.f,0.f},{0.f,0.f}};

#pragma unroll
        for (int l = 0; l < L; ++l) {
            const int sh = lvl_sh[l];
            const int hw = 1 << sh;
            const float fhw = (float)hw;

            float4 la = lp4[2 * l + 0];
            float4 lb = lp4[2 * l + 1];
            float4 wv = wp4[l];
            float lx[4] = {la.x, la.z, lb.x, lb.z};
            float ly[4] = {la.y, la.w, lb.y, lb.w};
            float wl[4] = {wv.x, wv.y, wv.z, wv.w};

            // per-level fp16 accumulator (<=16 hfma2 steps -> drift <=~4e-3)
            __half2 acch[4];
            acch[0] = __float2half2_rn(0.f);
            acch[1] = __float2half2_rn(0.f);
            acch[2] = __float2half2_rn(0.f);
            acch[3] = __float2half2_rn(0.f);

#pragma unroll
            for (int p = 0; p < P; ++p) {
                float x = lx[p] * fhw - 0.5f;
                float y = ly[p] * fhw - 0.5f;
                float xf = floorf(x), yf = floorf(y);
                float fx = x - xf, fy = y - yf;
                int x0 = (int)xf, y0 = (int)yf;
                int x1 = x0 + 1, y1 = y0 + 1;

                float vx0 = ((unsigned)x0 < (unsigned)hw) ? 1.f : 0.f;
                float vx1 = ((unsigned)x1 < (unsigned)hw) ? 1.f : 0.f;
                float vy0 = ((unsigned)y0 < (unsigned)hw) ? 1.f : 0.f;
                float vy1 = ((unsigned)y1 < (unsigned)hw) ? 1.f : 0.f;

                int cx0 = min(max(x0, 0), hw - 1);
                int cx1 = min(max(x1, 0), hw - 1);
                int cy0 = min(max(y0, 0), hw - 1);
                int cy1 = min(max(y1, 0), hw - 1);

                int r0 = cy0 << sh;
                int r1 = cy1 << sh;

                union U { uint4 u; __half2 h2[4]; };
                U u00, u01, u10, u11;

                if (l < 2) {
                    // global fp16 gather (pixel = 64 B)
                    const int start = lvl_start[l];
                    unsigned o00 = ((unsigned)(start + r0 + cx0) << 6) + coff;
                    unsigned o01 = ((unsigned)(start + r0 + cx1) << 6) + coff;
                    unsigned o10 = ((unsigned)(start + r1 + cx0) << 6) + coff;
                    unsigned o11 = ((unsigned)(start + r1 + cx1) << 6) + coff;
                    u00.u = *(const uint4*)(vb + o00);
                    u01.u = *(const uint4*)(vb + o01);
                    u10.u = *(const uint4*)(vb + o10);
                    u11.u = *(const uint4*)(vb + o11);
                } else {
                    // LDS gather (levels 2,3 staged; 64B-aligned bases)
                    const int lstart = lvl_lstart[l];
                    unsigned o00 = ((unsigned)(lstart + r0 + cx0) << 6) + coff;
                    unsigned o01 = ((unsigned)(lstart + r0 + cx1) << 6) + coff;
                    unsigned o10 = ((unsigned)(lstart + r1 + cx0) << 6) + coff;
                    unsigned o11 = ((unsigned)(lstart + r1 + cx1) << 6) + coff;
                    u00.u = *(const uint4*)(smem + o00);
                    u01.u = *(const uint4*)(smem + o01);
                    u10.u = *(const uint4*)(smem + o10);
                    u11.u = *(const uint4*)(smem + o11);
                }

                float wgt = wl[p];
                float w00 = (1.f - fx) * (1.f - fy) * wgt * vx0 * vy0;
                float w01 = fx * (1.f - fy) * wgt * vx1 * vy0;
                float w10 = (1.f - fx) * fy * wgt * vx0 * vy1;
                float w11 = fx * fy * wgt * vx1 * vy1;

                __half2 W00 = __float2half2_rn(w00);
                __half2 W01 = __float2half2_rn(w01);
                __half2 W10 = __float2half2_rn(w10);
                __half2 W11 = __float2half2_rn(w11);

#pragma unroll
                for (int j = 0; j < 4; ++j) {
                    acch[j] = __hfma2(u00.h2[j], W00, acch[j]);
                    acch[j] = __hfma2(u01.h2[j], W01, acch[j]);
                    acch[j] = __hfma2(u10.h2[j], W10, acch[j]);
                    acch[j] = __hfma2(u11.h2[j], W11, acch[j]);
                }
            }

            // fold level into f32 accumulator
#pragma unroll
            for (int j = 0; j < 4; ++j) {
                float2 t = __half22float2(acch[j]);
                acc[j].x += t.x;
                acc[j].y += t.y;
            }
        }

        // lane owns d[8*lane .. 8*lane+7] -> float4 chunks 2*lane, 2*lane+1
        float4* op = (float4*)out + bqh * (D / 4) + lane * 2;
        op[0] = make_float4(acc[0].x, acc[0].y, acc[1].x, acc[1].y);
        op[1] = make_float4(acc[2].x, acc[2].y, acc[3].x, acc[3].y);
    }
}

// ---------------- round-5 fp16 kernel (fallback if big-LDS attr fails) ------
__global__ __launch_bounds__(256) void msda_fwd_fp16_kernel(
    const __half* __restrict__ vw, const float* __restrict__ loc,
    const float* __restrict__ aw, float* __restrict__ out)
{
    constexpr int H = MSDA_H, D = MSDA_D, L = MSDA_L, P = MSDA_P;
    constexpr int S = MSDA_S, Q = MSDA_Q;
    const int lvl_sh[4]    = {7, 6, 5, 4};
    const int lvl_start[4] = {0, 16384, 20480, 21504};

    int i = blockIdx.x;
    int h = i & 7;
    int r = i >> 3;
    int b = r / MSDA_QBLK16;
    int qb = r - b * MSDA_QBLK16;

    int q = qb * 64 + (threadIdx.x >> 2);
    if (q >= Q) return;
    const int lane = threadIdx.x & 3;
    const unsigned coff = (unsigned)lane * 16;

    const size_t bqh = ((size_t)b * Q + q) * H + h;
    const float4* lp4 = (const float4*)(loc + bqh * (L * P * 2));
    const float4* wp4 = (const float4*)(aw  + bqh * (L * P));
    const char* vb = (const char*)(vw + (size_t)(b * H + h) * S * D);

    float2 acc[4] = {{0.f,0.f},{0.f,0.f},{0.f,0.f},{0.f,0.f}};

#pragma unroll
    for (int l = 0; l < L; ++l) {
        const int sh = lvl_sh[l];
        const int hw = 1 << sh;
        const float fhw = (float)hw;
        const int start = lvl_start[l];

        float4 la = lp4[2 * l + 0];
        float4 lb = lp4[2 * l + 1];
        float4 wv = wp4[l];
        float lx[4] = {la.x, la.z, lb.x, lb.z};
        float ly[4] = {la.y, la.w, lb.y, lb.w};
        float wl[4] = {wv.x, wv.y, wv.z, wv.w};

#pragma unroll
        for (int p = 0; p < P; ++p) {
            float x = lx[p] * fhw - 0.5f;
            float y = ly[p] * fhw - 0.5f;
            float xf = floorf(x), yf = floorf(y);
            float fx = x - xf, fy = y - yf;
            int x0 = (int)xf, y0 = (int)yf;
            int x1 = x0 + 1, y1 = y0 + 1;

            float vx0 = ((unsigned)x0 < (unsigned)hw) ? 1.f : 0.f;
            float vx1 = ((unsigned)x1 < (unsigned)hw) ? 1.f : 0.f;
            float vy0 = ((unsigned)y0 < (unsigned)hw) ? 1.f : 0.f;
            float vy1 = ((unsigned)y1 < (unsigned)hw) ? 1.f : 0.f;

            int cx0 = min(max(x0, 0), hw - 1);
            int cx1 = min(max(x1, 0), hw - 1);
            int cy0 = min(max(y0, 0), hw - 1);
            int cy1 = min(max(y1, 0), hw - 1);

            int r0 = start + (cy0 << sh);
            int r1 = start + (cy1 << sh);
            unsigned o00 = ((unsigned)(r0 + cx0) << 6) + coff;
            unsigned o01 = ((unsigned)(r0 + cx1) << 6) + coff;
            unsigned o10 = ((unsigned)(r1 + cx0) << 6) + coff;
            unsigned o11 = ((unsigned)(r1 + cx1) << 6) + coff;

            union U { uint4 u; __half2 h2[4]; };
            U u00, u01, u10, u11;
            u00.u = *(const uint4*)(vb + o00);
            u01.u = *(const uint4*)(vb + o01);
            u10.u = *(const uint4*)(vb + o10);
            u11.u = *(const uint4*)(vb + o11);

            float wgt = wl[p];
            float w00 = (1.f - fx) * (1.f - fy) * wgt * vx0 * vy0;
            float w01 = fx * (1.f - fy) * wgt * vx1 * vy0;
            float w10 = (1.f - fx) * fy * wgt * vx0 * vy1;
            float w11 = fx * fy * wgt * vx1 * vy1;

#pragma unroll
            for (int j = 0; j < 4; ++j) {
                float2 f00 = __half22float2(u00.h2[j]);
                float2 f01 = __half22float2(u01.h2[j]);
                float2 f10 = __half22float2(u10.h2[j]);
                float2 f11 = __half22float2(u11.h2[j]);
                acc[j].x += w00 * f00.x + w01 * f01.x + w10 * f10.x + w11 * f11.x;
                acc[j].y += w00 * f00.y + w01 * f01.y + w10 * f10.y + w11 * f11.y;
            }
        }
    }

    float4* op = (float4*)out + bqh * (D / 4) + lane * 2;
    op[0] = make_float4(acc[0].x, acc[0].y, acc[1].x, acc[1].y);
    op[1] = make_float4(acc[2].x, acc[2].y, acc[3].x, acc[3].y);
}

// ---------------- fp32 fallback (round-4 kernel) ----------------
__global__ __launch_bounds__(256, 4) void msda_fwd_fp32_kernel(
    const float* __restrict__ value, const float* __restrict__ loc,
    const float* __restrict__ aw, float* __restrict__ out)
{
    constexpr int H = MSDA_H, D = MSDA_D, L = MSDA_L, P = MSDA_P;
    constexpr int S = MSDA_S, Q = MSDA_Q;
    const int lvl_sh[4]    = {7, 6, 5, 4};
    const int lvl_start[4] = {0, 16384, 20480, 21504};

    int i = blockIdx.x;
    int h = i & 7;
    int r = i >> 3;
    int b = r / MSDA_QBLK32;
    int qb = r - b * MSDA_QBLK32;

    int q = qb * 32 + (threadIdx.x >> 3);
    if (q >= Q) return;
    const unsigned coff = (threadIdx.x & 7) * 16;

    const size_t bqh = ((size_t)b * Q + q) * H + h;
    const float4* lp4 = (const float4*)(loc + bqh * (L * P * 2));
    const float4* wp4 = (const float4*)(aw  + bqh * (L * P));
    const char* vb = (const char*)(value + ((size_t)b * S * H + h) * D);

    float4 acc = {0.f, 0.f, 0.f, 0.f};

#pragma unroll
    for (int l = 0; l < L; ++l) {
        const int sh = lvl_sh[l];
        const int hw = 1 << sh;
        const float fhw = (float)hw;
        const int start = lvl_start[l];

        float4 la = lp4[2 * l + 0];
        float4 lb = lp4[2 * l + 1];
        float4 wv = wp4[l];
        float lx[4] = {la.x, la.z, lb.x, lb.z};
        float ly[4] = {la.y, la.w, lb.y, lb.w};
        float wl[4] = {wv.x, wv.y, wv.z, wv.w};

#pragma unroll
        for (int p = 0; p < P; ++p) {
            float x = lx[p] * fhw - 0.5f;
            float y = ly[p] * fhw - 0.5f;
            float xf = floorf(x), yf = floorf(y);
            float fx = x - xf, fy = y - yf;
            int x0 = (int)xf, y0 = (int)yf;
            int x1 = x0 + 1, y1 = y0 + 1;

            float vx0 = ((unsigned)x0 < (unsigned)hw) ? 1.f : 0.f;
            float vx1 = ((unsigned)x1 < (unsigned)hw) ? 1.f : 0.f;
            float vy0 = ((unsigned)y0 < (unsigned)hw) ? 1.f : 0.f;
            float vy1 = ((unsigned)y1 < (unsigned)hw) ? 1.f : 0.f;

            int cx0 = min(max(x0, 0), hw - 1);
            int cx1 = min(max(x1, 0), hw - 1);
            int cy0 = min(max(y0, 0), hw - 1);
            int cy1 = min(max(y1, 0), hw - 1);

            float wgt = wl[p];
            float w00 = (1.f - fx) * (1.f - fy) * wgt * vx0 * vy0;
            float w01 = fx * (1.f - fy) * wgt * vx1 * vy0;
            float w10 = (1.f - fx) * fy * wgt * vx0 * vy1;
            float w11 = fx * fy * wgt * vx1 * vy1;

            int r0 = start + (cy0 << sh);
            int r1 = start + (cy1 << sh);
            unsigned o00 = ((unsigned)(r0 + cx0) << 10) + coff;
            unsigned o01 = ((unsigned)(r0 + cx1) << 10) + coff;
            unsigned o10 = ((unsigned)(r1 + cx0) << 10) + coff;
            unsigned o11 = ((unsigned)(r1 + cx1) << 10) + coff;

            float4 v00 = *(const float4*)(vb + o00);
            float4 v01 = *(const float4*)(vb + o01);
            float4 v10 = *(const float4*)(vb + o10);
            float4 v11 = *(const float4*)(vb + o11);

            acc.x += w00 * v00.x + w01 * v01.x + w10 * v10.x + w11 * v11.x;
            acc.y += w00 * v00.y + w01 * v01.y + w10 * v10.y + w11 * v11.y;
            acc.z += w00 * v00.z + w01 * v01.z + w10 * v10.z + w11 * v11.z;
            acc.w += w00 * v00.w + w01 * v01.w + w10 * v10.w + w11 * v11.w;
        }
    }

    ((float4*)out)[bqh * (D / 4) + (threadIdx.x & 7)] = acc;
}

extern "C" void kernel_launch(void* const* d_in, const int* in_sizes, int n_in,
                              void* d_out, int out_size, void* d_ws, size_t ws_size,
                              hipStream_t stream) {
    const float* value = (const float*)d_in[0];
    const float* loc = (const float*)d_in[3];
    const float* aw  = (const float*)d_in[4];
    float* out = (float*)d_out;

    // one-time: allow 80KB dynamic LDS on the LDS-path kernel
    static int lds_ok = -1;
    if (lds_ok < 0) {
        hipError_t e = hipFuncSetAttribute(
            reinterpret_cast<const void*>(msda_fwd_lds_kernel),
            hipFuncAttributeMaxDynamicSharedMemorySize, MSDA_LDS_BYTES);
        lds_ok = (e == hipSuccess) ? 1 : 0;
    }

    const size_t need = (size_t)MSDA_B * MSDA_H * MSDA_S * MSDA_D * sizeof(__half);
    if (ws_size >= need) {
        __half* vw = (__half*)d_ws;
        msda_convert_kernel<<<(MSDA_B * MSDA_S * MSDA_H * MSDA_D / 4 + 255) / 256,
                              256, 0, stream>>>(value, vw);
        if (lds_ok) {
            const int grid = MSDA_B * MSDA_H * MSDA_NB;   // 256 = 1 block/CU
            msda_fwd_lds_kernel<<<grid, 512, MSDA_LDS_BYTES, stream>>>(vw, loc, aw, out);
        } else {
            const int grid = 8 * MSDA_B * MSDA_QBLK16;    // 5024
            msda_fwd_fp16_kernel<<<grid, 256, 0, stream>>>(vw, loc, aw, out);
        }
    } else {
        const int grid = 8 * MSDA_B * MSDA_QBLK32;        // 10016
        msda_fwd_fp32_kernel<<<grid, 256, 0, stream>>>(value, loc, aw, out);
    }
}